// Round 1
// baseline (625.211 us; speedup 1.0000x reference)
//
#include <hip/hip_runtime.h>
#include <hip/hip_bf16.h>

#define BB  1024
#define NIn 2048
#define NHn 4096
#define NOn 1024
#define KK  6144   // NIn + NHn

typedef __attribute__((ext_vector_type(8))) short short8;
typedef __attribute__((ext_vector_type(4))) float f32x4;

__device__ inline unsigned short f2bf(float f) {
  union { float f; unsigned u; } v; v.f = f;
  unsigned u = v.u;
  return (unsigned short)((u + 0x7fffu + ((u >> 16) & 1u)) >> 16);
}

__device__ inline void gload_lds16(const void* g, void* l) {
  __builtin_amdgcn_global_load_lds(
      (const __attribute__((address_space(1))) void*)g,
      (__attribute__((address_space(3))) void*)l, 16, 0, 0);
}

__device__ inline float sigf(float x) {
  return __builtin_amdgcn_rcpf(1.f + __expf(-x));
}
__device__ inline float tanh_f(float x) {
  // tanh(x) = 1 - 2/(exp(2x)+1); saturates correctly at +/-1 (no inf/inf NaN)
  return 1.f - 2.f * __builtin_amdgcn_rcpf(1.f + __expf(2.f * x));
}

// ---------------- conversion: fp32 -> bf16, concatenated layouts ----------------
// A_cat [BB, KK]  = [i | h]
// Wh_cat[NHn, KK] = [W_i2h | W_h2h]
// Wo_cat[NOn, KK] = [W_i2o | W_h2o]
__global__ __launch_bounds__(256) void conv_kernel(
    const float* __restrict__ i_in, const float* __restrict__ h_in,
    const float* __restrict__ Wi2h, const float* __restrict__ Wh2h,
    const float* __restrict__ Wi2o, const float* __restrict__ Wh2o,
    unsigned short* __restrict__ A_cat, unsigned short* __restrict__ Wh_cat,
    unsigned short* __restrict__ Wo_cat) {
  const int CHA  = BB  * (KK / 8);
  const int CHWH = NHn * (KK / 8);
  const int CHWO = NOn * (KK / 8);
  int q = blockIdx.x * 256 + threadIdx.x;
  if (q >= CHA + CHWH + CHWO) return;
  const float *s1, *s2;
  unsigned short* d;
  int p;
  if (q < CHA)             { p = q;              s1 = i_in; s2 = h_in;  d = A_cat; }
  else if (q < CHA + CHWH) { p = q - CHA;        s1 = Wi2h; s2 = Wh2h;  d = Wh_cat; }
  else                     { p = q - CHA - CHWH; s1 = Wi2o; s2 = Wh2o;  d = Wo_cat; }
  int row = p / (KK / 8);
  int j = (p - row * (KK / 8)) * 8;
  const float* s = (j < NIn) ? (s1 + (size_t)row * NIn + j)
                             : (s2 + (size_t)row * (KK - NIn) + (j - NIn));
  f32x4 x0 = *(const f32x4*)s;
  f32x4 x1 = *(const f32x4*)(s + 4);
  short8 v;
#pragma unroll
  for (int t = 0; t < 4; ++t) {
    v[t]     = (short)f2bf(x0[t]);
    v[4 + t] = (short)f2bf(x1[t]);
  }
  *(short8*)(d + (size_t)p * 8) = v;
}

// ---------------- fused GEMM (bf16 MFMA) + per-node LSTM epilogue ----------------
// blocks 0..255: hidden nodes (N=4096); blocks 256..319: output nodes (N=1024)
__global__ __launch_bounds__(256) void gemm_lstm(
    const unsigned short* __restrict__ A,     // [BB, KK] bf16
    const unsigned short* __restrict__ Wh,    // [NHn, KK] bf16
    const unsigned short* __restrict__ Wo,    // [NOn, KK] bf16
    const float* __restrict__ b_i2h, const float* __restrict__ b_h2h,
    const float* __restrict__ b_i2o, const float* __restrict__ b_h2o,
    const float* __restrict__ h_in, const float* __restrict__ o_in,
    const float* __restrict__ h_cells, const float* __restrict__ o_cells,
    const float* __restrict__ Wih_h, const float* __restrict__ Whh_h,
    const float* __restrict__ bias_h, const float* __restrict__ Whr_h,
    const float* __restrict__ Wih_o, const float* __restrict__ Whh_o,
    const float* __restrict__ bias_o, const float* __restrict__ Whr_o,
    float* __restrict__ out_h, float* __restrict__ out_o,
    float* __restrict__ out_hc, float* __restrict__ out_oc) {
  __shared__ __align__(16) unsigned short sA[128 * 32];
  __shared__ __align__(16) unsigned short sB[128 * 32];

  const int bid = blockIdx.x;
  const bool hid = bid < 256;
  const int lb = hid ? bid : bid - 256;
  const int bm = lb & 7;     // 8 row blocks (B/128)
  const int bn = lb >> 3;    // 32 or 8 col blocks
  const unsigned short* Wmat = hid ? Wh : Wo;
  const int N = hid ? NHn : NOn;
  const int row0 = bm * 128;
  const int col0 = bn * 128;

  const int tid = threadIdx.x;
  const int w = tid >> 6;        // wave 0..3
  const int lane = tid & 63;
  const int wm = (w & 1) * 64;   // wave M offset in tile
  const int wn = (w >> 1) * 64;  // wave N offset in tile
  const int fr = lane & 15;
  const int quad = lane >> 4;
  const int kq = quad * 8;

  f32x4 acc[4][4];
#pragma unroll
  for (int mi = 0; mi < 4; ++mi)
#pragma unroll
    for (int ni = 0; ni < 4; ++ni)
      acc[mi][ni] = (f32x4){0.f, 0.f, 0.f, 0.f};

  for (int k0 = 0; k0 < KK; k0 += 32) {
    __syncthreads();  // protect LDS from overwrite while prev iter still reading
#pragma unroll
    for (int j = 0; j < 2; ++j) {
      const int q = w * 128 + j * 64 + lane;  // chunk id in [0,512)
      const int r = q >> 2;                   // tile row
      const int c = (q & 3) * 8;              // k element offset
      gload_lds16(A + (size_t)(row0 + r) * KK + (k0 + c),
                  &sA[(size_t)(w * 128 + j * 64) * 8]);
      gload_lds16(Wmat + (size_t)(col0 + r) * KK + (k0 + c),
                  &sB[(size_t)(w * 128 + j * 64) * 8]);
    }
    __syncthreads();  // drains vmcnt(0) before barrier -> LDS valid

    short8 af[4], bf[4];
#pragma unroll
    for (int mi = 0; mi < 4; ++mi)
      af[mi] = *(const short8*)&sA[(wm + mi * 16 + fr) * 32 + kq];
#pragma unroll
    for (int ni = 0; ni < 4; ++ni)
      bf[ni] = *(const short8*)&sB[(wn + ni * 16 + fr) * 32 + kq];
#pragma unroll
    for (int mi = 0; mi < 4; ++mi)
#pragma unroll
      for (int ni = 0; ni < 4; ++ni)
        acc[mi][ni] = __builtin_amdgcn_mfma_f32_16x16x32_bf16(
            af[mi], bf[ni], acc[mi][ni], 0, 0, 0);
  }

  // ---------------- epilogue: bias + relu + per-node LSTM ----------------
  const float* bA  = hid ? b_i2h : b_i2o;
  const float* bBp = hid ? b_h2h : b_h2o;
  const float* hpm = hid ? h_in : o_in;
  const float* cel = hid ? h_cells : o_cells;
  const float* Wih = hid ? Wih_h : Wih_o;
  const float* Whh = hid ? Whh_h : Whh_o;
  const float* bia = hid ? bias_h : bias_o;
  const float* Whr = hid ? Whr_h : Whr_o;
  float* outv = hid ? out_h : out_o;
  float* outc = hid ? out_hc : out_oc;

#pragma unroll
  for (int ni = 0; ni < 4; ++ni) {
    const int n = col0 + wn + ni * 16 + fr;  // node index (C col = lane&15)
    const float bsum = bA[n] + bBp[n];
    f32x4 wi[4], wh[4], bi[4];
#pragma unroll
    for (int g = 0; g < 4; ++g) {
      wi[g] = *(const f32x4*)(Wih + (size_t)n * 16 + g * 4);
      wh[g] = *(const f32x4*)(Whh + (size_t)n * 16 + g * 4);
      bi[g] = *(const f32x4*)(bia + (size_t)n * 16 + g * 4);
    }
    const f32x4 wr = *(const f32x4*)(Whr + (size_t)n * 4);
#pragma unroll
    for (int mi = 0; mi < 4; ++mi) {
      const int b0 = row0 + wm + mi * 16 + quad * 4;  // 4 consecutive batch rows
      const float* cpp = cel + ((size_t)n * BB + b0) * 4;
      f32x4 cp[4];
#pragma unroll
      for (int r = 0; r < 4; ++r) cp[r] = *(const f32x4*)(cpp + r * 4);
#pragma unroll
      for (int r = 0; r < 4; ++r) {
        const int b = b0 + r;
        float x = fmaxf(acc[mi][ni][r] + bsum, 0.f);  // inh (post-ReLU)
        float hp = hpm[(size_t)b * N + n];
        f32x4 cn;
        float hsum = 0.f;
#pragma unroll
        for (int c = 0; c < 4; ++c) {
          float gi = sigf(  x * wi[0][c] + hp * wh[0][c] + bi[0][c]);
          float gf = sigf(  x * wi[1][c] + hp * wh[1][c] + bi[1][c]);
          float gg = tanh_f(x * wi[2][c] + hp * wh[2][c] + bi[2][c]);
          float go = sigf(  x * wi[3][c] + hp * wh[3][c] + bi[3][c]);
          float cv = gf * cp[r][c] + gi * gg;
          cn[c] = cv;
          hsum += go * tanh_f(cv) * wr[c];
        }
        *(f32x4*)(outc + ((size_t)n * BB + b) * 4) = cn;  // new cells [N,B,C]
        outv[(size_t)b * N + n] = hsum;                   // new h/o [B,N]
      }
    }
  }
}

extern "C" void kernel_launch(void* const* d_in, const int* in_sizes, int n_in,
                              void* d_out, int out_size, void* d_ws, size_t ws_size,
                              hipStream_t stream) {
  const float* i_in    = (const float*)d_in[0];
  const float* h_in    = (const float*)d_in[1];
  const float* o_in    = (const float*)d_in[2];
  const float* h_cells = (const float*)d_in[3];
  const float* o_cells = (const float*)d_in[4];
  const float* W_i2h   = (const float*)d_in[5];
  const float* b_i2h   = (const float*)d_in[6];
  const float* W_h2h   = (const float*)d_in[7];
  const float* b_h2h   = (const float*)d_in[8];
  const float* W_i2o   = (const float*)d_in[9];
  const float* b_i2o   = (const float*)d_in[10];
  const float* W_h2o   = (const float*)d_in[11];
  const float* b_h2o   = (const float*)d_in[12];
  const float* Wih_h   = (const float*)d_in[13];
  const float* Whh_h   = (const float*)d_in[14];
  const float* bias_h  = (const float*)d_in[15];
  const float* Whr_h   = (const float*)d_in[16];
  const float* Wih_o   = (const float*)d_in[17];
  const float* Whh_o   = (const float*)d_in[18];
  const float* bias_o  = (const float*)d_in[19];
  const float* Whr_o   = (const float*)d_in[20];

  unsigned short* A_cat  = (unsigned short*)d_ws;
  unsigned short* Wh_cat = A_cat + (size_t)BB * KK;
  unsigned short* Wo_cat = Wh_cat + (size_t)NHn * KK;

  float* out_h  = (float*)d_out;
  float* out_o  = out_h + (size_t)BB * NHn;
  float* out_hc = out_o + (size_t)BB * NOn;
  float* out_oc = out_hc + (size_t)NHn * BB * 4;

  const int convchunks = (BB + NHn + NOn) * (KK / 8);
  conv_kernel<<<(convchunks + 255) / 256, 256, 0, stream>>>(
      i_in, h_in, W_i2h, W_h2h, W_i2o, W_h2o, A_cat, Wh_cat, Wo_cat);

  gemm_lstm<<<320, 256, 0, stream>>>(
      A_cat, Wh_cat, Wo_cat, b_i2h, b_h2h, b_i2o, b_h2o, h_in, o_in, h_cells,
      o_cells, Wih_h, Whh_h, bias_h, Whr_h, Wih_o, Whh_o, bias_o, Whr_o,
      out_h, out_o, out_hc, out_oc);
}

// Round 2
// 491.989 us; speedup vs baseline: 1.2708x; 1.2708x over previous
//
#include <hip/hip_runtime.h>
#include <hip/hip_bf16.h>

#define BB  1024
#define NIn 2048
#define NHn 4096
#define NOn 1024
#define KK  6144   // NIn + NHn

typedef __attribute__((ext_vector_type(8))) short short8;
typedef __attribute__((ext_vector_type(4))) float f32x4;

__device__ inline unsigned short f2bf(float f) {
  union { float f; unsigned u; } v; v.f = f;
  unsigned u = v.u;
  return (unsigned short)((u + 0x7fffu + ((u >> 16) & 1u)) >> 16);
}

__device__ inline void gload_lds16(const void* g, void* l) {
  __builtin_amdgcn_global_load_lds(
      (const __attribute__((address_space(1))) void*)g,
      (__attribute__((address_space(3))) void*)l, 16, 0, 0);
}

__device__ inline float sigf(float x) {
  return __builtin_amdgcn_rcpf(1.f + __expf(-x));
}
__device__ inline float tanh_f(float x) {
  return 1.f - 2.f * __builtin_amdgcn_rcpf(1.f + __expf(2.f * x));
}

// ---------------- conversion: fp32 -> bf16, concatenated layouts ----------------
__global__ __launch_bounds__(256) void conv_kernel(
    const float* __restrict__ i_in, const float* __restrict__ h_in,
    const float* __restrict__ Wi2h, const float* __restrict__ Wh2h,
    const float* __restrict__ Wi2o, const float* __restrict__ Wh2o,
    unsigned short* __restrict__ A_cat, unsigned short* __restrict__ Wh_cat,
    unsigned short* __restrict__ Wo_cat) {
  const int CHA  = BB  * (KK / 8);
  const int CHWH = NHn * (KK / 8);
  const int CHWO = NOn * (KK / 8);
  int q = blockIdx.x * 256 + threadIdx.x;
  if (q >= CHA + CHWH + CHWO) return;
  const float *s1, *s2;
  unsigned short* d;
  int p;
  if (q < CHA)             { p = q;              s1 = i_in; s2 = h_in;  d = A_cat; }
  else if (q < CHA + CHWH) { p = q - CHA;        s1 = Wi2h; s2 = Wh2h;  d = Wh_cat; }
  else                     { p = q - CHA - CHWH; s1 = Wi2o; s2 = Wh2o;  d = Wo_cat; }
  int row = p / (KK / 8);
  int j = (p - row * (KK / 8)) * 8;
  const float* s = (j < NIn) ? (s1 + (size_t)row * NIn + j)
                             : (s2 + (size_t)row * (KK - NIn) + (j - NIn));
  f32x4 x0 = *(const f32x4*)s;
  f32x4 x1 = *(const f32x4*)(s + 4);
  short8 v;
#pragma unroll
  for (int t = 0; t < 4; ++t) {
    v[t]     = (short)f2bf(x0[t]);
    v[4 + t] = (short)f2bf(x1[t]);
  }
  *(short8*)(d + (size_t)p * 8) = v;
}

// ---------------- fused GEMM (bf16 MFMA) + per-node LSTM epilogue ----------------
// Tile 128M x 64N, BK=64, XOR-8 LDS swizzle. Grid 640:
// blocks 0..511: hidden (N=4096); 512..639: output (N=1024)
__global__ __launch_bounds__(256) void gemm_lstm(
    const unsigned short* __restrict__ A,     // [BB, KK] bf16
    const unsigned short* __restrict__ Wh,    // [NHn, KK] bf16
    const unsigned short* __restrict__ Wo,    // [NOn, KK] bf16
    const float* __restrict__ b_i2h, const float* __restrict__ b_h2h,
    const float* __restrict__ b_i2o, const float* __restrict__ b_h2o,
    const float* __restrict__ h_in, const float* __restrict__ o_in,
    const float* __restrict__ h_cells, const float* __restrict__ o_cells,
    const float* __restrict__ Wih_h, const float* __restrict__ Whh_h,
    const float* __restrict__ bias_h, const float* __restrict__ Whr_h,
    const float* __restrict__ Wih_o, const float* __restrict__ Whh_o,
    const float* __restrict__ bias_o, const float* __restrict__ Whr_o,
    float* __restrict__ out_h, float* __restrict__ out_o,
    float* __restrict__ out_hc, float* __restrict__ out_oc) {
  // row stride 64 halfs = 128 B = 8 chunks of 16 B; chunk c stored at slot c^(row&7)
  __shared__ __align__(16) unsigned short sA[128 * 64];  // 16 KB
  __shared__ __align__(16) unsigned short sB[64 * 64];   // 8 KB

  const int bid = blockIdx.x;
  const bool hid = bid < 512;
  const int lb = hid ? bid : bid - 512;
  const int bm = lb & 7;     // B/128 = 8 row blocks
  const int bn = lb >> 3;    // 64 or 16 col blocks (N-tile 64)
  const unsigned short* Wmat = hid ? Wh : Wo;
  const int N = hid ? NHn : NOn;
  const int row0 = bm * 128;
  const int col0 = bn * 64;

  const int tid = threadIdx.x;
  const int w = tid >> 6;        // wave 0..3
  const int lane = tid & 63;
  const int wm = (w & 1) * 64;   // wave M offset (2x2 wave grid over 128x64)
  const int wn = (w >> 1) * 32;  // wave N offset
  const int fr = lane & 15;
  const int quad = lane >> 4;

  f32x4 acc[4][2];
#pragma unroll
  for (int mi = 0; mi < 4; ++mi)
#pragma unroll
    for (int ni = 0; ni < 2; ++ni)
      acc[mi][ni] = (f32x4){0.f, 0.f, 0.f, 0.f};

  // precompute per-lane staging descriptors
  // A: 1024 chunks, 16 instrs; wave w handles j=0..3, q = w*256 + j*64 + lane
  // B: 512 chunks, 8 instrs;  wave w handles j=0..1, q = w*128 + j*64 + lane
  int aQ[4], aOff[4];
#pragma unroll
  for (int j = 0; j < 4; ++j) {
    int q = w * 256 + j * 64 + lane;
    int r = q >> 3, cs = q & 7;
    int cg = cs ^ (r & 7);
    aQ[j] = (w * 256 + j * 64) * 8;                    // LDS base (halfs), uniform
    aOff[j] = (row0 + r) * KK + cg * 8;                // global element offset (+k0)
  }
  int bQ[2], bOff[2];
#pragma unroll
  for (int j = 0; j < 2; ++j) {
    int q = w * 128 + j * 64 + lane;
    int r = q >> 3, cs = q & 7;
    int cg = cs ^ (r & 7);
    bQ[j] = (w * 128 + j * 64) * 8;
    bOff[j] = (col0 + r) * KK + cg * 8;
  }

  for (int k0 = 0; k0 < KK; k0 += 64) {
    __syncthreads();
#pragma unroll
    for (int j = 0; j < 4; ++j)
      gload_lds16(A + (size_t)aOff[j] + k0, &sA[aQ[j]]);
#pragma unroll
    for (int j = 0; j < 2; ++j)
      gload_lds16(Wmat + (size_t)bOff[j] + k0, &sB[bQ[j]]);
    __syncthreads();

    short8 af[2][4], bf[2][2];
#pragma unroll
    for (int kk = 0; kk < 2; ++kk) {
#pragma unroll
      for (int mi = 0; mi < 4; ++mi) {
        int r = wm + mi * 16 + fr;
        int c = (kk * 4 + quad) ^ (fr & 7);
        af[kk][mi] = *(const short8*)&sA[r * 64 + c * 8];
      }
#pragma unroll
      for (int ni = 0; ni < 2; ++ni) {
        int r = wn + ni * 16 + fr;
        int c = (kk * 4 + quad) ^ (fr & 7);
        bf[kk][ni] = *(const short8*)&sB[r * 64 + c * 8];
      }
    }
#pragma unroll
    for (int kk = 0; kk < 2; ++kk)
#pragma unroll
      for (int mi = 0; mi < 4; ++mi)
#pragma unroll
        for (int ni = 0; ni < 2; ++ni)
          acc[mi][ni] = __builtin_amdgcn_mfma_f32_16x16x32_bf16(
              af[kk][mi], bf[kk][ni], acc[mi][ni], 0, 0, 0);
  }

  // ---------------- epilogue: bias + relu + per-node LSTM ----------------
  const float* bA  = hid ? b_i2h : b_i2o;
  const float* bBp = hid ? b_h2h : b_h2o;
  const float* hpm = hid ? h_in : o_in;
  const float* cel = hid ? h_cells : o_cells;
  const float* Wih = hid ? Wih_h : Wih_o;
  const float* Whh = hid ? Whh_h : Whh_o;
  const float* bia = hid ? bias_h : bias_o;
  const float* Whr = hid ? Whr_h : Whr_o;
  float* outv = hid ? out_h : out_o;
  float* outc = hid ? out_hc : out_oc;

#pragma unroll
  for (int ni = 0; ni < 2; ++ni) {
    const int n = col0 + wn + ni * 16 + fr;
    const float bsum = bA[n] + bBp[n];
    f32x4 wi[4], wh[4], bi[4];
#pragma unroll
    for (int g = 0; g < 4; ++g) {
      wi[g] = *(const f32x4*)(Wih + (size_t)n * 16 + g * 4);
      wh[g] = *(const f32x4*)(Whh + (size_t)n * 16 + g * 4);
      bi[g] = *(const f32x4*)(bia + (size_t)n * 16 + g * 4);
    }
    const f32x4 wr = *(const f32x4*)(Whr + (size_t)n * 4);
#pragma unroll
    for (int mi = 0; mi < 4; ++mi) {
      const int b0 = row0 + wm + mi * 16 + quad * 4;
      const float* cpp = cel + ((size_t)n * BB + b0) * 4;
      f32x4 cp[4];
#pragma unroll
      for (int r = 0; r < 4; ++r) cp[r] = *(const f32x4*)(cpp + r * 4);
#pragma unroll
      for (int r = 0; r < 4; ++r) {
        const int b = b0 + r;
        float x = fmaxf(acc[mi][ni][r] + bsum, 0.f);
        float hp = hpm[(size_t)b * N + n];
        f32x4 cn;
        float hsum = 0.f;
#pragma unroll
        for (int c = 0; c < 4; ++c) {
          float gi = sigf(  x * wi[0][c] + hp * wh[0][c] + bi[0][c]);
          float gf = sigf(  x * wi[1][c] + hp * wh[1][c] + bi[1][c]);
          float gg = tanh_f(x * wi[2][c] + hp * wh[2][c] + bi[2][c]);
          float go = sigf(  x * wi[3][c] + hp * wh[3][c] + bi[3][c]);
          float cv = gf * cp[r][c] + gi * gg;
          cn[c] = cv;
          hsum += go * tanh_f(cv) * wr[c];
        }
        *(f32x4*)(outc + ((size_t)n * BB + b) * 4) = cn;
        outv[(size_t)b * N + n] = hsum;
      }
    }
  }
}

extern "C" void kernel_launch(void* const* d_in, const int* in_sizes, int n_in,
                              void* d_out, int out_size, void* d_ws, size_t ws_size,
                              hipStream_t stream) {
  const float* i_in    = (const float*)d_in[0];
  const float* h_in    = (const float*)d_in[1];
  const float* o_in    = (const float*)d_in[2];
  const float* h_cells = (const float*)d_in[3];
  const float* o_cells = (const float*)d_in[4];
  const float* W_i2h   = (const float*)d_in[5];
  const float* b_i2h   = (const float*)d_in[6];
  const float* W_h2h   = (const float*)d_in[7];
  const float* b_h2h   = (const float*)d_in[8];
  const float* W_i2o   = (const float*)d_in[9];
  const float* b_i2o   = (const float*)d_in[10];
  const float* W_h2o   = (const float*)d_in[11];
  const float* b_h2o   = (const float*)d_in[12];
  const float* Wih_h   = (const float*)d_in[13];
  const float* Whh_h   = (const float*)d_in[14];
  const float* bias_h  = (const float*)d_in[15];
  const float* Whr_h   = (const float*)d_in[16];
  const float* Wih_o   = (const float*)d_in[17];
  const float* Whh_o   = (const float*)d_in[18];
  const float* bias_o  = (const float*)d_in[19];
  const float* Whr_o   = (const float*)d_in[20];

  unsigned short* A_cat  = (unsigned short*)d_ws;
  unsigned short* Wh_cat = A_cat + (size_t)BB * KK;
  unsigned short* Wo_cat = Wh_cat + (size_t)NHn * KK;

  float* out_h  = (float*)d_out;
  float* out_o  = out_h + (size_t)BB * NHn;
  float* out_hc = out_o + (size_t)BB * NOn;
  float* out_oc = out_hc + (size_t)NHn * BB * 4;

  const int convchunks = (BB + NHn + NOn) * (KK / 8);
  conv_kernel<<<(convchunks + 255) / 256, 256, 0, stream>>>(
      i_in, h_in, W_i2h, W_h2h, W_i2o, W_h2o, A_cat, Wh_cat, Wo_cat);

  gemm_lstm<<<640, 256, 0, stream>>>(
      A_cat, Wh_cat, Wo_cat, b_i2h, b_h2h, b_i2o, b_h2o, h_in, o_in, h_cells,
      o_cells, Wih_h, Whh_h, bias_h, Whr_h, Wih_o, Whh_o, bias_o, Whr_o,
      out_h, out_o, out_hc, out_oc);
}